// Round 2
// baseline (283.608 us; speedup 1.0000x reference)
//
#include <hip/hip_runtime.h>
#include <hip/hip_bf16.h>

typedef __hip_bfloat16 bf16;
typedef __attribute__((ext_vector_type(8))) short short8;
typedef __attribute__((ext_vector_type(4))) float f32x4;
typedef __attribute__((ext_vector_type(4))) unsigned short us4;

#define EMB 1024
#define HEADS 16
#define HD 64
#define BATCH 2
#define SEQ 2048
#define ROWS (BATCH * SEQ) /* 4096 */

__device__ __forceinline__ void gload_lds16(const void* g, void* l) {
  __builtin_amdgcn_global_load_lds(
      (const __attribute__((address_space(1))) void*)g,
      (__attribute__((address_space(3))) void*)l, 16, 0, 0);
}

__device__ __forceinline__ unsigned short f2bf(float x) {
  bf16 h = __float2bfloat16(x);
  return __builtin_bit_cast(unsigned short, h);
}

// f32 -> bf16 (RN), vectorized 4-wide.
__global__ __launch_bounds__(256) void cvt_kernel(const float* __restrict__ in,
                                                  unsigned short* __restrict__ out,
                                                  int n4) {
  int i = blockIdx.x * 256 + threadIdx.x;
  if (i >= n4) return;
  const float4 v = ((const float4*)in)[i];
  us4 o;
  o[0] = f2bf(v.x);
  o[1] = f2bf(v.y);
  o[2] = f2bf(v.z);
  o[3] = f2bf(v.w);
  ((us4*)out)[i] = o;
}

// C[M,*] = A[M,K] @ B[N,K]^T + bias (f32), bf16 in, f32 accum.
// MODE 0: scatter into Q/K/V [B,H,SEQ,HD] bf16, Q scaled by 0.125.
// MODE 1: f32 out: outF[row*N+col] = acc + bias.
template <int MODE>
__global__ __launch_bounds__(256) void gemm_bt(
    const bf16* __restrict__ A, const bf16* __restrict__ B,
    const float* __restrict__ bias,
    unsigned short* __restrict__ out0, unsigned short* __restrict__ out1,
    unsigned short* __restrict__ out2, float* __restrict__ outF, int N, int K) {
  __shared__ unsigned short As[128 * 64];
  __shared__ unsigned short Bs[128 * 64];
  const int lane = threadIdx.x & 63;
  const int wv = threadIdx.x >> 6;
  const int m0 = blockIdx.y * 128;
  const int n0 = blockIdx.x * 128;
  const int wr = wv >> 1, wc = wv & 1;

  f32x4 acc[4][4] = {};

  const int srow = lane >> 3;       // 0..7
  const int scol = (lane & 7) * 8;  // element col within K-step
  const bf16* Ag = A + (size_t)(m0 + wv * 32 + srow) * K + scol;
  const bf16* Bg = B + (size_t)(n0 + wv * 32 + srow) * K + scol;

  for (int k0 = 0; k0 < K; k0 += 64) {
#pragma unroll
    for (int i = 0; i < 4; ++i) {
      gload_lds16(Ag + (size_t)(i * 8) * K + k0, As + (wv * 32 + i * 8) * 64);
      gload_lds16(Bg + (size_t)(i * 8) * K + k0, Bs + (wv * 32 + i * 8) * 64);
    }
    __syncthreads();
#pragma unroll
    for (int kk = 0; kk < 2; ++kk) {
      short8 a[4], b[4];
#pragma unroll
      for (int i = 0; i < 4; ++i)
        a[i] = *(const short8*)(As + (wr * 64 + i * 16 + (lane & 15)) * 64 +
                                kk * 32 + (lane >> 4) * 8);
#pragma unroll
      for (int i = 0; i < 4; ++i)
        b[i] = *(const short8*)(Bs + (wc * 64 + i * 16 + (lane & 15)) * 64 +
                                kk * 32 + (lane >> 4) * 8);
#pragma unroll
      for (int mi = 0; mi < 4; ++mi)
#pragma unroll
        for (int ni = 0; ni < 4; ++ni)
          acc[mi][ni] = __builtin_amdgcn_mfma_f32_16x16x32_bf16(
              a[mi], b[ni], acc[mi][ni], 0, 0, 0);
    }
    __syncthreads();
  }

#pragma unroll
  for (int mi = 0; mi < 4; ++mi) {
#pragma unroll
    for (int ni = 0; ni < 4; ++ni) {
      const int col = n0 + wc * 64 + ni * 16 + (lane & 15);
      const float bv = bias[col];
#pragma unroll
      for (int r = 0; r < 4; ++r) {
        const int row = m0 + wr * 64 + mi * 16 + (lane >> 4) * 4 + r;
        float v = acc[mi][ni][r] + bv;
        if (MODE == 0) {
          const int part = col >> 10;
          const int h = (col & 1023) >> 6;
          const int hd = col & 63;
          const int bb = row >> 11;
          const int tok = row & 2047;
          unsigned short* dst = (part == 0) ? out0 : (part == 1) ? out1 : out2;
          if (part == 0) v *= 0.125f;  // fold attention scale into Q
          dst[(((size_t)(bb * HEADS + h)) * SEQ + tok) * HD + hd] = f2bf(v);
        } else {
          outF[(size_t)row * N + col] = v;
        }
      }
    }
  }
}

// Flash attention: grid (B*H, SEQ/64), 256 threads (4 waves x 16 q-rows).
__global__ __launch_bounds__(256) void attn_kernel(
    const bf16* __restrict__ Q, const bf16* __restrict__ Kx,
    const bf16* __restrict__ Vx, unsigned short* __restrict__ O) {
  __shared__ unsigned short Ks[64 * 64];      // [kvrow][dim]
  __shared__ unsigned short Vt[64 * 64];      // [dim][kvrow]
  __shared__ unsigned short Ps[4][16 * 64];   // per-wave P tile [qrow][kvcol]
  const int lane = threadIdx.x & 63;
  const int wv = threadIdx.x >> 6;
  const int bh = blockIdx.x;  // b*HEADS + h
  const int q0 = blockIdx.y * 64;
  const int b = bh >> 4;
  const int h = bh & 15;
  const size_t base = (size_t)bh * SEQ * HD;

  // Q fragments for this wave's 16 rows (A-operand layout), K-dim = 64 -> 2 frags
  short8 qf[2];
  {
    const bf16* qp =
        Q + base + (size_t)(q0 + wv * 16 + (lane & 15)) * HD + (lane >> 4) * 8;
    qf[0] = *(const short8*)qp;
    qf[1] = *(const short8*)(qp + 32);
  }

  f32x4 o[4] = {};
  float mrow[4], lrow[4];
#pragma unroll
  for (int r = 0; r < 4; ++r) {
    mrow[r] = -3.0e38f;
    lrow[r] = 0.f;
  }

  for (int kv0 = 0; kv0 < SEQ; kv0 += 64) {
    const bf16* Kt = Kx + base + (size_t)kv0 * HD;     // contiguous 64x64 tile
    const bf16* Vtile = Vx + base + (size_t)kv0 * HD;  // contiguous 64x64 tile
#pragma unroll
    for (int j = 0; j < 2; ++j) {  // K tile: linear memcpy via global_load_lds
      const int c = j * 4 + wv;
      gload_lds16(Kt + c * 512 + lane * 8, Ks + c * 512);
    }
#pragma unroll
    for (int j = 0; j < 2; ++j) {  // V tile: transpose into Vt[dim][kvrow]
      const int idx = threadIdx.x + j * 256;
      const int kvr = idx >> 3;
      const int d0 = (idx & 7) * 8;
      short8 vv = *(const short8*)(Vtile + kvr * HD + d0);
#pragma unroll
      for (int e = 0; e < 8; ++e)
        Vt[(d0 + e) * 64 + kvr] = (unsigned short)vv[e];
    }
    __syncthreads();

    // S = Q * K^T  (Q already scaled by 0.125)
    f32x4 s[4] = {};
#pragma unroll
    for (int kk = 0; kk < 2; ++kk) {
#pragma unroll
      for (int n = 0; n < 4; ++n) {
        short8 kb = *(const short8*)(Ks + (n * 16 + (lane & 15)) * 64 +
                                     kk * 32 + (lane >> 4) * 8);
        s[n] = __builtin_amdgcn_mfma_f32_16x16x32_bf16(qf[kk], kb, s[n], 0, 0, 0);
      }
    }

    // online softmax (rows live in 16-lane groups; xor masks 1,2,4,8 stay in-group)
    unsigned short* Pw = Ps[wv];
#pragma unroll
    for (int r = 0; r < 4; ++r) {
      float mx = fmaxf(fmaxf(s[0][r], s[1][r]), fmaxf(s[2][r], s[3][r]));
      mx = fmaxf(mx, __shfl_xor(mx, 1));
      mx = fmaxf(mx, __shfl_xor(mx, 2));
      mx = fmaxf(mx, __shfl_xor(mx, 4));
      mx = fmaxf(mx, __shfl_xor(mx, 8));
      const float mnew = fmaxf(mrow[r], mx);
      const float corr = __expf(mrow[r] - mnew);
      mrow[r] = mnew;
      float rs = 0.f;
#pragma unroll
      for (int n = 0; n < 4; ++n) {
        const float p = __expf(s[n][r] - mnew);
        s[n][r] = p;
        rs += p;
      }
      rs += __shfl_xor(rs, 1);
      rs += __shfl_xor(rs, 2);
      rs += __shfl_xor(rs, 4);
      rs += __shfl_xor(rs, 8);
      lrow[r] = lrow[r] * corr + rs;
#pragma unroll
      for (int n = 0; n < 4; ++n) o[n][r] *= corr;
#pragma unroll
      for (int n = 0; n < 4; ++n)
        Pw[((lane >> 4) * 4 + r) * 64 + n * 16 + (lane & 15)] = f2bf(s[n][r]);
    }
    __syncthreads();  // order P writes (and Ks reads) before PV / next staging

    // O += P * V
#pragma unroll
    for (int kk = 0; kk < 2; ++kk) {
      short8 pa =
          *(const short8*)(Pw + (lane & 15) * 64 + kk * 32 + (lane >> 4) * 8);
#pragma unroll
      for (int n = 0; n < 4; ++n) {
        short8 vb = *(const short8*)(Vt + (n * 16 + (lane & 15)) * 64 +
                                     kk * 32 + (lane >> 4) * 8);
        o[n] = __builtin_amdgcn_mfma_f32_16x16x32_bf16(pa, vb, o[n], 0, 0, 0);
      }
    }
    __syncthreads();
  }

  float inv[4];
#pragma unroll
  for (int r = 0; r < 4; ++r) inv[r] = 1.0f / lrow[r];
#pragma unroll
  for (int n = 0; n < 4; ++n)
#pragma unroll
    for (int r = 0; r < 4; ++r) {
      const int row = q0 + wv * 16 + (lane >> 4) * 4 + r;
      O[((size_t)b * SEQ + row) * EMB + h * HD + n * 16 + (lane & 15)] =
          f2bf(o[n][r] * inv[r]);
    }
}

extern "C" void kernel_launch(void* const* d_in, const int* in_sizes, int n_in,
                              void* d_out, int out_size, void* d_ws,
                              size_t ws_size, hipStream_t stream) {
  const float* x = (const float*)d_in[0];
  const float* qkv_w = (const float*)d_in[1];
  const float* qkv_b = (const float*)d_in[2];
  const float* proj_w = (const float*)d_in[3];
  const float* proj_b = (const float*)d_in[4];

  const size_t n_x = (size_t)ROWS * EMB;        // 4,194,304
  const size_t n_qkvw = (size_t)3 * EMB * EMB;  // 3,145,728
  const size_t n_projw = (size_t)EMB * EMB;     // 1,048,576
  const size_t elems = (size_t)BATCH * HEADS * SEQ * HD;  // 4,194,304

  unsigned short* xb = (unsigned short*)d_ws;
  unsigned short* wqkv = xb + n_x;
  unsigned short* wproj = wqkv + n_qkvw;
  unsigned short* Qw = wproj + n_projw;
  unsigned short* Kw = Qw + elems;
  unsigned short* Vw = Kw + elems;
  unsigned short* Ow = Vw + elems;  // [B, SEQ, EMB]

  // 0) f32 -> bf16 conversions
  cvt_kernel<<<(int)(n_x / 4 + 255) / 256, 256, 0, stream>>>(x, xb, (int)(n_x / 4));
  cvt_kernel<<<(int)(n_qkvw / 4 + 255) / 256, 256, 0, stream>>>(qkv_w, wqkv,
                                                                (int)(n_qkvw / 4));
  cvt_kernel<<<(int)(n_projw / 4 + 255) / 256, 256, 0, stream>>>(
      proj_w, wproj, (int)(n_projw / 4));

  // 1) QKV projection: [4096,1024] x [3072,1024]^T -> scatter Q/K/V
  dim3 g1(3 * EMB / 128, ROWS / 128);  // 24 x 32
  gemm_bt<0><<<g1, 256, 0, stream>>>((const bf16*)xb, (const bf16*)wqkv, qkv_b,
                                     Qw, Kw, Vw, nullptr, 3 * EMB, EMB);

  // 2) flash attention -> Ow [B, SEQ, EMB]
  dim3 g2(BATCH * HEADS, SEQ / 64);  // 32 x 32
  attn_kernel<<<g2, 256, 0, stream>>>((const bf16*)Qw, (const bf16*)Kw,
                                      (const bf16*)Vw, Ow);

  // 3) output projection: [4096,1024] x [1024,1024]^T + bias -> d_out (f32)
  dim3 g3(EMB / 128, ROWS / 128);  // 8 x 32
  gemm_bt<1><<<g3, 256, 0, stream>>>((const bf16*)Ow, (const bf16*)wproj,
                                     proj_b, nullptr, nullptr, nullptr,
                                     (float*)d_out, EMB, EMB);
}

// Round 3
// 224.737 us; speedup vs baseline: 1.2620x; 1.2620x over previous
//
#include <hip/hip_runtime.h>
#include <hip/hip_bf16.h>

typedef __hip_bfloat16 bf16;
typedef __attribute__((ext_vector_type(8))) short short8;
typedef __attribute__((ext_vector_type(4))) float f32x4;
typedef __attribute__((ext_vector_type(4))) unsigned short us4;

#define EMB 1024
#define HEADS 16
#define HD 64
#define BATCH 2
#define SEQ 2048
#define ROWS (BATCH * SEQ) /* 4096 */

__device__ __forceinline__ void gload_lds16(const void* g, void* l) {
  __builtin_amdgcn_global_load_lds(
      (const __attribute__((address_space(1))) void*)g,
      (__attribute__((address_space(3))) void*)l, 16, 0, 0);
}

__device__ __forceinline__ unsigned short f2bf(float x) {
  bf16 h = __float2bfloat16(x);
  return __builtin_bit_cast(unsigned short, h);
}

// f32 -> bf16 (RN), vectorized 4-wide.
__global__ __launch_bounds__(256) void cvt_kernel(const float* __restrict__ in,
                                                  unsigned short* __restrict__ out,
                                                  int n4) {
  int i = blockIdx.x * 256 + threadIdx.x;
  if (i >= n4) return;
  const float4 v = ((const float4*)in)[i];
  us4 o;
  o[0] = f2bf(v.x);
  o[1] = f2bf(v.y);
  o[2] = f2bf(v.z);
  o[3] = f2bf(v.w);
  ((us4*)out)[i] = o;
}

// C[M,*] = A[M,K] @ B[N,K]^T + bias (f32), bf16 in, f32 accum.
// MODE 0: scatter Q [bh,tok,hd] (x0.125), K [bh,tok,hd], V TRANSPOSED [bh,hd,tok].
// MODE 1: f32 out: outF[row*N+col] = acc + bias.
template <int MODE>
__global__ __launch_bounds__(256) void gemm_bt(
    const bf16* __restrict__ A, const bf16* __restrict__ B,
    const float* __restrict__ bias,
    unsigned short* __restrict__ out0, unsigned short* __restrict__ out1,
    unsigned short* __restrict__ out2, float* __restrict__ outF, int N, int K) {
  __shared__ unsigned short As[128 * 64];
  __shared__ unsigned short Bs[128 * 64];
  const int lane = threadIdx.x & 63;
  const int wv = threadIdx.x >> 6;
  const int m0 = blockIdx.y * 128;
  const int n0 = blockIdx.x * 128;
  const int wr = wv >> 1, wc = wv & 1;

  f32x4 acc[4][4] = {};

  const int srow = lane >> 3;       // 0..7
  const int scol = (lane & 7) * 8;  // element col within K-step
  const bf16* Ag = A + (size_t)(m0 + wv * 32 + srow) * K + scol;
  const bf16* Bg = B + (size_t)(n0 + wv * 32 + srow) * K + scol;

  for (int k0 = 0; k0 < K; k0 += 64) {
#pragma unroll
    for (int i = 0; i < 4; ++i) {
      gload_lds16(Ag + (size_t)(i * 8) * K + k0, As + (wv * 32 + i * 8) * 64);
      gload_lds16(Bg + (size_t)(i * 8) * K + k0, Bs + (wv * 32 + i * 8) * 64);
    }
    __syncthreads();
#pragma unroll
    for (int kk = 0; kk < 2; ++kk) {
      short8 a[4], b[4];
#pragma unroll
      for (int i = 0; i < 4; ++i)
        a[i] = *(const short8*)(As + (wr * 64 + i * 16 + (lane & 15)) * 64 +
                                kk * 32 + (lane >> 4) * 8);
#pragma unroll
      for (int i = 0; i < 4; ++i)
        b[i] = *(const short8*)(Bs + (wc * 64 + i * 16 + (lane & 15)) * 64 +
                                kk * 32 + (lane >> 4) * 8);
#pragma unroll
      for (int mi = 0; mi < 4; ++mi)
#pragma unroll
        for (int ni = 0; ni < 4; ++ni)
          acc[mi][ni] = __builtin_amdgcn_mfma_f32_16x16x32_bf16(
              a[mi], b[ni], acc[mi][ni], 0, 0, 0);
    }
    __syncthreads();
  }

#pragma unroll
  for (int mi = 0; mi < 4; ++mi) {
#pragma unroll
    for (int ni = 0; ni < 4; ++ni) {
      const int col = n0 + wc * 64 + ni * 16 + (lane & 15);
      const float bv = bias[col];
#pragma unroll
      for (int r = 0; r < 4; ++r) {
        const int row = m0 + wr * 64 + mi * 16 + (lane >> 4) * 4 + r;
        float v = acc[mi][ni][r] + bv;
        if (MODE == 0) {
          const int part = col >> 10;
          const int h = (col & 1023) >> 6;
          const int hd = col & 63;
          const int bb = row >> 11;
          const int tok = row & 2047;
          const size_t bh = (size_t)(bb * HEADS + h);
          if (part == 0) {
            out0[(bh * SEQ + tok) * HD + hd] = f2bf(v * 0.125f);
          } else if (part == 1) {
            out1[(bh * SEQ + tok) * HD + hd] = f2bf(v);
          } else {  // V: store transposed [bh][hd][tok]
            out2[(bh * HD + hd) * SEQ + tok] = f2bf(v);
          }
        } else {
          outF[(size_t)row * N + col] = v;
        }
      }
    }
  }
}

// Barrier-free flash attention. grid (B*H, SEQ/128), 256 thr = 4 indep waves.
// Each wave: 32 q-rows. K [bh,kv,hd] and Vt [bh,hd,kv] fragments read straight
// from global (L2-resident: per-XCD head affinity via blockIdx.x%8). Only LDS
// use is the per-wave P C->A layout round-trip, XOR-swizzled (slot ^= row&7).
__global__ __launch_bounds__(256, 2) void attn_kernel(
    const bf16* __restrict__ Q, const bf16* __restrict__ Kx,
    const bf16* __restrict__ Vt, unsigned short* __restrict__ O) {
  __shared__ unsigned short Ps[4][32 * 64];
  const int lane = threadIdx.x & 63;
  const int wv = threadIdx.x >> 6;
  const int c = lane & 15;   // fragment row-within-16 / C col
  const int q4 = lane >> 4;  // quarter
  const int bh = blockIdx.x;
  const int b = bh >> 4;
  const int h = bh & 15;
  const int q0 = blockIdx.y * 128 + wv * 32;
  const size_t base = (size_t)bh * SEQ * HD;
  unsigned short* Pw = Ps[wv];

  // Q fragments: rows q0 + mi*16 + c, k = kk*32 + q4*8 (Q pre-scaled by 0.125)
  short8 qf[2][2];
#pragma unroll
  for (int mi = 0; mi < 2; ++mi)
#pragma unroll
    for (int kk = 0; kk < 2; ++kk)
      qf[mi][kk] = *(const short8*)(Q + base + (size_t)(q0 + mi * 16 + c) * HD +
                                    kk * 32 + q4 * 8);

  f32x4 o[2][4] = {};
  float mrow[2][4], lrow[2][4];
#pragma unroll
  for (int mi = 0; mi < 2; ++mi)
#pragma unroll
    for (int r = 0; r < 4; ++r) {
      mrow[mi][r] = -3.0e38f;
      lrow[mi][r] = 0.f;
    }

  for (int kv0 = 0; kv0 < SEQ; kv0 += 64) {
    // K fragments straight from global: row kv0+n*16+c, k = kk*32+q4*8
    short8 kf[2][4];
#pragma unroll
    for (int kk = 0; kk < 2; ++kk)
#pragma unroll
      for (int n = 0; n < 4; ++n)
        kf[kk][n] = *(const short8*)(Kx + base +
                                     (size_t)(kv0 + n * 16 + c) * HD +
                                     kk * 32 + q4 * 8);
    // issue V fragments early (consumed after softmax): Vt row d=n*16+c
    short8 vf[2][4];
#pragma unroll
    for (int kk = 0; kk < 2; ++kk)
#pragma unroll
      for (int n = 0; n < 4; ++n)
        vf[kk][n] = *(const short8*)(Vt + base + (size_t)(n * 16 + c) * SEQ +
                                     kv0 + kk * 32 + q4 * 8);

    // S = Q K^T
    f32x4 s[2][4] = {};
#pragma unroll
    for (int kk = 0; kk < 2; ++kk)
#pragma unroll
      for (int n = 0; n < 4; ++n)
#pragma unroll
        for (int mi = 0; mi < 2; ++mi)
          s[mi][n] = __builtin_amdgcn_mfma_f32_16x16x32_bf16(
              qf[mi][kk], kf[kk][n], s[mi][n], 0, 0, 0);

    // online softmax; rows of mi live in 16-lane groups (xor 1,2,4,8)
#pragma unroll
    for (int mi = 0; mi < 2; ++mi) {
      float mx[4];
#pragma unroll
      for (int r = 0; r < 4; ++r) {
        float v = fmaxf(fmaxf(s[mi][0][r], s[mi][1][r]),
                        fmaxf(s[mi][2][r], s[mi][3][r]));
        v = fmaxf(v, __shfl_xor(v, 1));
        v = fmaxf(v, __shfl_xor(v, 2));
        v = fmaxf(v, __shfl_xor(v, 4));
        v = fmaxf(v, __shfl_xor(v, 8));
        mx[r] = v;
      }
      bool lc = true;
#pragma unroll
      for (int r = 0; r < 4; ++r) lc = lc && (mx[r] <= mrow[mi][r] + 8.0f);
      if (!__all(lc)) {  // T13 defer-max: rescale only on real max growth
#pragma unroll
        for (int r = 0; r < 4; ++r) {
          const float mnew = fmaxf(mrow[mi][r], mx[r]);
          const float corr = __expf(mrow[mi][r] - mnew);
          mrow[mi][r] = mnew;
          lrow[mi][r] *= corr;
#pragma unroll
          for (int n = 0; n < 4; ++n) o[mi][n][r] *= corr;
        }
      }
#pragma unroll
      for (int r = 0; r < 4; ++r) {
        const int row = mi * 16 + q4 * 4 + r;
        float rs = 0.f;
#pragma unroll
        for (int n = 0; n < 4; ++n) {
          const float p = __expf(s[mi][n][r] - mrow[mi][r]);
          rs += p;
          const int col = n * 16 + c;
          Pw[row * 64 + (((col >> 3) ^ (row & 7)) << 3) + (col & 7)] = f2bf(p);
        }
        rs += __shfl_xor(rs, 1);
        rs += __shfl_xor(rs, 2);
        rs += __shfl_xor(rs, 4);
        rs += __shfl_xor(rs, 8);
        lrow[mi][r] += rs;
      }
    }

    // P back as A-fragments (swizzled read), then O += P V
    short8 pa[2][2];
#pragma unroll
    for (int mi = 0; mi < 2; ++mi)
#pragma unroll
      for (int kk = 0; kk < 2; ++kk) {
        const int row = mi * 16 + c;
        const int slot = (kk * 4 + q4) ^ (row & 7);
        pa[mi][kk] = *(const short8*)(Pw + row * 64 + slot * 8);
      }
#pragma unroll
    for (int kk = 0; kk < 2; ++kk)
#pragma unroll
      for (int n = 0; n < 4; ++n)
#pragma unroll
        for (int mi = 0; mi < 2; ++mi)
          o[mi][n] = __builtin_amdgcn_mfma_f32_16x16x32_bf16(
              pa[mi][kk], vf[kk][n], o[mi][n], 0, 0, 0);
  }

  // normalize + write O [B, tok, EMB]
#pragma unroll
  for (int mi = 0; mi < 2; ++mi) {
    float inv[4];
#pragma unroll
    for (int r = 0; r < 4; ++r) inv[r] = 1.0f / lrow[mi][r];
#pragma unroll
    for (int n = 0; n < 4; ++n)
#pragma unroll
      for (int r = 0; r < 4; ++r) {
        const int row = q0 + mi * 16 + q4 * 4 + r;
        O[((size_t)b * SEQ + row) * EMB + h * HD + n * 16 + c] =
            f2bf(o[mi][n][r] * inv[r]);
      }
  }
}

extern "C" void kernel_launch(void* const* d_in, const int* in_sizes, int n_in,
                              void* d_out, int out_size, void* d_ws,
                              size_t ws_size, hipStream_t stream) {
  const float* x = (const float*)d_in[0];
  const float* qkv_w = (const float*)d_in[1];
  const float* qkv_b = (const float*)d_in[2];
  const float* proj_w = (const float*)d_in[3];
  const float* proj_b = (const float*)d_in[4];

  const size_t n_x = (size_t)ROWS * EMB;
  const size_t n_qkvw = (size_t)3 * EMB * EMB;
  const size_t n_projw = (size_t)EMB * EMB;
  const size_t elems = (size_t)BATCH * HEADS * SEQ * HD;

  unsigned short* xb = (unsigned short*)d_ws;
  unsigned short* wqkv = xb + n_x;
  unsigned short* wproj = wqkv + n_qkvw;
  unsigned short* Qw = wproj + n_projw;
  unsigned short* Kw = Qw + elems;
  unsigned short* Vw = Kw + elems;  // transposed [bh][hd][tok]
  unsigned short* Ow = Vw + elems;  // [B, SEQ, EMB]

  // 0) f32 -> bf16 conversions
  cvt_kernel<<<(int)(n_x / 4 + 255) / 256, 256, 0, stream>>>(x, xb,
                                                             (int)(n_x / 4));
  cvt_kernel<<<(int)(n_qkvw / 4 + 255) / 256, 256, 0, stream>>>(
      qkv_w, wqkv, (int)(n_qkvw / 4));
  cvt_kernel<<<(int)(n_projw / 4 + 255) / 256, 256, 0, stream>>>(
      proj_w, wproj, (int)(n_projw / 4));

  // 1) QKV projection -> Q/K scatter + V transposed scatter
  dim3 g1(3 * EMB / 128, ROWS / 128);  // 24 x 32
  gemm_bt<0><<<g1, 256, 0, stream>>>((const bf16*)xb, (const bf16*)wqkv, qkv_b,
                                     Qw, Kw, Vw, nullptr, 3 * EMB, EMB);

  // 2) barrier-free flash attention -> Ow [B, SEQ, EMB]
  dim3 g2(BATCH * HEADS, SEQ / 128);  // 32 x 16
  attn_kernel<<<g2, 256, 0, stream>>>((const bf16*)Qw, (const bf16*)Kw,
                                      (const bf16*)Vw, Ow);

  // 3) output projection + bias -> d_out (f32)
  dim3 g3(EMB / 128, ROWS / 128);  // 8 x 32
  gemm_bt<1><<<g3, 256, 0, stream>>>((const bf16*)Ow, (const bf16*)wproj,
                                     proj_b, nullptr, nullptr, nullptr,
                                     (float*)d_out, EMB, EMB);
}